// Round 2
// baseline (7305.807 us; speedup 1.0000x reference)
//
#include <hip/hip_runtime.h>

#define T_SEQ 2048
#define NMORPH 6144
#define EMB 100
#define HID 128
#define GATES 512
#define LDA0 304
#define XPD 1024
#define TAGS 50

__device__ __forceinline__ float sigm(float x) {
  return 1.0f / (1.0f + __expf(-x));
}
__device__ __forceinline__ float tanh_f(float x) {
  x = fminf(fmaxf(x, -9.0f), 9.0f);
  float e2 = __expf(2.0f * x);
  return (e2 - 1.0f) / (e2 + 1.0f);
}

// ---------------- kernel 1: segment-sum of morpheme embeddings into inp[:,0:100]
__global__ void k_toksum(const float* __restrict__ W_wv,
                         const int* __restrict__ morp_ids,
                         const int* __restrict__ seg,
                         float* __restrict__ inp) {
  const int t = blockIdx.x;
  const int d = threadIdx.x;  // 0..127
  int a = 0, b = NMORPH;
  while (a < b) { int m = (a + b) >> 1; if (seg[m] < t) a = m + 1; else b = m; }
  const int lo = a;
  b = NMORPH;
  while (a < b) { int m = (a + b) >> 1; if (seg[m] <= t) a = m + 1; else b = m; }
  const int hi = a;
  if (d < EMB) {
    float s = 0.0f;
    for (int m = lo; m < hi; ++m)
      s += W_wv[(size_t)morp_ids[m] * EMB + d];
    inp[(size_t)t * LDA0 + d] = s;
  }
}

// ---------------- kernel 2: fill inp cols 100..303 (pred vec, dp emb, feat, pad)
__global__ void k_fill(const float* __restrict__ dp_table,
                       const int* __restrict__ dp_in,
                       const float* __restrict__ feat,
                       const int* __restrict__ pred_idx,
                       float* __restrict__ inp) {
  const int t = blockIdx.x;
  const int c = threadIdx.x;  // 0..255 -> col 100+c
  if (c >= 204) return;
  const int col = 100 + c;
  float v;
  if (col < 200)      v = inp[(size_t)pred_idx[0] * LDA0 + (col - 100)];
  else if (col < 264) v = dp_table[dp_in[t] * 64 + (col - 200)];
  else if (col < 300) v = feat[t * 36 + (col - 264)];
  else                v = 0.0f;  // pad cols 300..303
  inp[(size_t)t * LDA0 + col] = v;
}

// ---------------- kernel 3: xp[M x 1024] = A[M x K] @ [Wf;Wb]^T + [bf;bb]
__global__ __launch_bounds__(256) void k_gemm(
    const float* __restrict__ A, int lda, int K,
    const float* __restrict__ Wf, const float* __restrict__ Wb,
    const float* __restrict__ bf, const float* __restrict__ bb,
    float* __restrict__ out) {
  constexpr int BK = 16, LDT = 68;
  __shared__ float As[BK][LDT];
  __shared__ float Bs[BK][LDT];
  const int tid = threadIdx.x;
  const int tx = tid & 15, ty = tid >> 4;
  const int bm = blockIdx.x * 64;
  const int n0 = blockIdx.y * 64;
  const float* __restrict__ W  = (n0 < GATES) ? Wf : Wb;
  const float* __restrict__ bs = (n0 < GATES) ? bf : bb;
  const int nw = (n0 < GATES) ? n0 : n0 - GATES;
  const int ar = tid >> 2;
  const int ak = (tid & 3) * 4;
  float acc[4][4] = {};
  const int ktiles = (K + BK - 1) / BK;
  for (int kt = 0; kt < ktiles; ++kt) {
    const int k0 = kt * BK;
    float4 av = *(const float4*)&A[(size_t)(bm + ar) * lda + k0 + ak];
    float4 bv = make_float4(0.f, 0.f, 0.f, 0.f);
    if (k0 + ak < K)
      bv = *(const float4*)&W[(size_t)(nw + ar) * K + k0 + ak];
    __syncthreads();
    As[ak + 0][ar] = av.x; As[ak + 1][ar] = av.y;
    As[ak + 2][ar] = av.z; As[ak + 3][ar] = av.w;
    Bs[ak + 0][ar] = bv.x; Bs[ak + 1][ar] = bv.y;
    Bs[ak + 2][ar] = bv.z; Bs[ak + 3][ar] = bv.w;
    __syncthreads();
#pragma unroll
    for (int kk = 0; kk < BK; ++kk) {
      float4 a4 = *(const float4*)&As[kk][ty * 4];
      float4 b4 = *(const float4*)&Bs[kk][tx * 4];
      float a_[4] = {a4.x, a4.y, a4.z, a4.w};
      float b_[4] = {b4.x, b4.y, b4.z, b4.w};
#pragma unroll
      for (int i = 0; i < 4; ++i)
#pragma unroll
        for (int j = 0; j < 4; ++j)
          acc[i][j] = fmaf(a_[i], b_[j], acc[i][j]);
    }
  }
  const float4 bias4 = *(const float4*)&bs[nw + tx * 4];
#pragma unroll
  for (int i = 0; i < 4; ++i) {
    float4 o;
    o.x = acc[i][0] + bias4.x;
    o.y = acc[i][1] + bias4.y;
    o.z = acc[i][2] + bias4.z;
    o.w = acc[i][3] + bias4.w;
    *(float4*)&out[(size_t)(bm + ty * 4 + i) * XPD + n0 + tx * 4] = o;
  }
}

// ---------------- kernel 4: persistent LSTM recurrence
// 256 threads (4 waves, 1 wave/SIMD, VGPR cap 512): thread t owns gate rows
// t and t+256. Rows 0..255 = i|f (sigmoid for every thread); row+256 is
// g (tanh, waves 0-1) or o (sigmoid, waves 2-3) -> wave-uniform activation.
// Weights persistent in VGPRs (2x32 float4 = 256 regs). h broadcast via LDS
// uniform ds_read_b128, reused for both rows (128 broadcast reads/step/CU).
__global__ __launch_bounds__(256, 1) void k_lstm(
    const float* __restrict__ xp,     // [T][1024] (f cols 0:512, b cols 512:1024)
    const float* __restrict__ whh_f,  // [512][128]
    const float* __restrict__ whh_b,
    float* __restrict__ hout) {       // [T][256] (f cols 0:128, b cols 128:256)
  const int dir = blockIdx.x;
  const int tid = threadIdx.x;        // 0..255
  const int ra = tid;                 // i/f gate row
  const int rb = tid + 256;           // g/o gate row
  const float* __restrict__ whh = dir ? whh_b : whh_f;
  const int xofs = dir * GATES;
  const int hofs = dir * HID;

  __shared__ __align__(16) float lh[HID];
  __shared__ float lg[GATES];

  // persistent weights: 2 gate rows per thread, 256 VGPRs
  float4 wa[32], wb[32];
  {
    const float4* rowa = (const float4*)(whh + (size_t)ra * HID);
    const float4* rowb = (const float4*)(whh + (size_t)rb * HID);
#pragma unroll
    for (int q = 0; q < 32; ++q) wa[q] = rowa[q];
#pragma unroll
    for (int q = 0; q < 32; ++q) wb[q] = rowb[q];
  }

  float c = 0.0f;
  if (tid < HID) lh[tid] = 0.0f;
  __syncthreads();

  float xa_c[8], xb_c[8], xa_n[8], xb_n[8];
#pragma unroll
  for (int u = 0; u < 8; ++u) {
    const int tt = dir ? (T_SEQ - 1 - u) : u;
    xa_c[u] = xp[(size_t)tt * XPD + xofs + ra];
    xb_c[u] = xp[(size_t)tt * XPD + xofs + rb];
  }

  for (int t0 = 0; t0 < T_SEQ; t0 += 8) {
    // prefetch next group of xp (raw barriers keep these in flight)
    const int tb = (t0 + 8 < T_SEQ) ? t0 + 8 : 0;
#pragma unroll
    for (int u = 0; u < 8; ++u) {
      const int t = tb + u;
      const int tt = dir ? (T_SEQ - 1 - t) : t;
      xa_n[u] = xp[(size_t)tt * XPD + xofs + ra];
      xb_n[u] = xp[(size_t)tt * XPD + xofs + rb];
    }
#pragma unroll
    for (int u = 0; u < 8; ++u) {
      const int t = t0 + u;
      const int tt = dir ? (T_SEQ - 1 - t) : t;
      // dot(w_row, h_prev) for both rows: 32 broadcast ds_read_b128, 8 chains
      const float4* lh4 = (const float4*)lh;
      float a0 = 0.f, a1 = 0.f, a2 = 0.f, a3 = 0.f;
      float b0 = 0.f, b1 = 0.f, b2 = 0.f, b3 = 0.f;
#pragma unroll
      for (int q = 0; q < 32; ++q) {
        float4 hv = lh4[q];
        a0 = fmaf(wa[q].x, hv.x, a0);
        a1 = fmaf(wa[q].y, hv.y, a1);
        a2 = fmaf(wa[q].z, hv.z, a2);
        a3 = fmaf(wa[q].w, hv.w, a3);
        b0 = fmaf(wb[q].x, hv.x, b0);
        b1 = fmaf(wb[q].y, hv.y, b1);
        b2 = fmaf(wb[q].z, hv.z, b2);
        b3 = fmaf(wb[q].w, hv.w, b3);
      }
      float ga = xa_c[u] + ((a0 + a1) + (a2 + a3));
      float gb = xb_c[u] + ((b0 + b1) + (b2 + b3));
      // activations: rows 0..255 are i/f -> sigmoid (all threads);
      // row+256 is g (tanh) for tid<128, o (sigmoid) for tid>=128.
      float ga_n = sigm(ga);
      float gb_n = (tid < HID) ? tanh_f(gb) : sigm(gb);
      lg[ra] = ga_n;
      lg[rb] = gb_n;
      asm volatile("s_waitcnt lgkmcnt(0)" ::: "memory");
      __builtin_amdgcn_s_barrier();
      if (tid < HID) {
        float gi = lg[tid];
        float gf = lg[HID + tid];
        float gg = lg[2 * HID + tid];
        float go = lg[3 * HID + tid];
        c = gf * c + gi * gg;
        float h = go * tanh_f(c);
        lh[tid] = h;
        hout[(size_t)tt * 256 + hofs + tid] = h;  // fire-and-forget store
      }
      asm volatile("s_waitcnt lgkmcnt(0)" ::: "memory");
      __builtin_amdgcn_s_barrier();
      xa_c[u] = xa_n[u];
      xb_c[u] = xb_n[u];
    }
  }
}

// ---------------- kernel 5: tag_space = h2 @ W_out^T + b_out
__global__ void k_out(const float* __restrict__ h2,
                      const float* __restrict__ Wout,
                      const float* __restrict__ bout,
                      float* __restrict__ out) {
  __shared__ __align__(16) float hrow[256];
  const int t = blockIdx.x;
  const int tid = threadIdx.x;  // 64
  *(float4*)&hrow[tid * 4] = *(const float4*)&h2[(size_t)t * 256 + tid * 4];
  __syncthreads();
  if (tid < TAGS) {
    float acc = bout[tid];
    const float* w = &Wout[(size_t)tid * 256];
#pragma unroll 8
    for (int k = 0; k < 256; k += 4) {
      float4 wv = *(const float4*)&w[k];
      acc += hrow[k] * wv.x + hrow[k + 1] * wv.y + hrow[k + 2] * wv.z +
             hrow[k + 3] * wv.w;
    }
    out[(size_t)t * TAGS + tid] = acc;
  }
}

extern "C" void kernel_launch(void* const* d_in, const int* in_sizes, int n_in,
                              void* d_out, int out_size, void* d_ws, size_t ws_size,
                              hipStream_t stream) {
  const int*   morp_ids = (const int*)d_in[0];
  const int*   seg      = (const int*)d_in[1];
  const int*   pred_idx = (const int*)d_in[2];
  const int*   dp_in    = (const int*)d_in[3];
  const float* feat     = (const float*)d_in[4];
  const float* W_wv     = (const float*)d_in[5];
  const float* dp_table = (const float*)d_in[6];
  const float* W_out    = (const float*)d_in[7];
  const float* b_out    = (const float*)d_in[8];
  const float* w_ih_l0f = (const float*)d_in[9];
  const float* w_hh_l0f = (const float*)d_in[10];
  const float* b_l0f    = (const float*)d_in[11];
  const float* w_ih_l0b = (const float*)d_in[12];
  const float* w_hh_l0b = (const float*)d_in[13];
  const float* b_l0b    = (const float*)d_in[14];
  const float* w_ih_l1f = (const float*)d_in[15];
  const float* w_hh_l1f = (const float*)d_in[16];
  const float* b_l1f    = (const float*)d_in[17];
  const float* w_ih_l1b = (const float*)d_in[18];
  const float* w_hh_l1b = (const float*)d_in[19];
  const float* b_l1b    = (const float*)d_in[20];
  float* out = (float*)d_out;

  float* ws  = (float*)d_ws;
  float* inp = ws;                      // 2048*304
  float* xp  = inp + 2048 * LDA0;       // 2048*1024 (reused for both layers)
  float* h1  = xp + 2048 * XPD;         // 2048*256
  float* h2  = h1 + 2048 * 256;         // 2048*256

  k_toksum<<<2048, 128, 0, stream>>>(W_wv, morp_ids, seg, inp);
  k_fill<<<2048, 256, 0, stream>>>(dp_table, dp_in, feat, pred_idx, inp);

  dim3 gg(32, 16);
  k_gemm<<<gg, 256, 0, stream>>>(inp, LDA0, 300, w_ih_l0f, w_ih_l0b, b_l0f, b_l0b, xp);
  k_lstm<<<2, 256, 0, stream>>>(xp, w_hh_l0f, w_hh_l0b, h1);
  k_gemm<<<gg, 256, 0, stream>>>(h1, 256, 256, w_ih_l1f, w_ih_l1b, b_l1f, b_l1b, xp);
  k_lstm<<<2, 256, 0, stream>>>(xp, w_hh_l1f, w_hh_l1b, h2);
  k_out<<<2048, 64, 0, stream>>>(h2, W_out, b_out, out);
}

// Round 3
// 3702.150 us; speedup vs baseline: 1.9734x; 1.9734x over previous
//
#include <hip/hip_runtime.h>

#define T_SEQ 2048
#define NMORPH 6144
#define EMB 100
#define HID 128
#define GATES 512
#define LDA0 304
#define XPD 1024
#define TAGS 50

__device__ __forceinline__ float sigm(float x) {
  return 1.0f / (1.0f + __expf(-x));
}
__device__ __forceinline__ float tanh_f(float x) {
  x = fminf(fmaxf(x, -9.0f), 9.0f);
  float e2 = __expf(2.0f * x);
  return (e2 - 1.0f) / (e2 + 1.0f);
}

// ---------------- kernel 1: segment-sum of morpheme embeddings into inp[:,0:100]
__global__ void k_toksum(const float* __restrict__ W_wv,
                         const int* __restrict__ morp_ids,
                         const int* __restrict__ seg,
                         float* __restrict__ inp) {
  const int t = blockIdx.x;
  const int d = threadIdx.x;  // 0..127
  int a = 0, b = NMORPH;
  while (a < b) { int m = (a + b) >> 1; if (seg[m] < t) a = m + 1; else b = m; }
  const int lo = a;
  b = NMORPH;
  while (a < b) { int m = (a + b) >> 1; if (seg[m] <= t) a = m + 1; else b = m; }
  const int hi = a;
  if (d < EMB) {
    float s = 0.0f;
    for (int m = lo; m < hi; ++m)
      s += W_wv[(size_t)morp_ids[m] * EMB + d];
    inp[(size_t)t * LDA0 + d] = s;
  }
}

// ---------------- kernel 2: fill inp cols 100..303 (pred vec, dp emb, feat, pad)
__global__ void k_fill(const float* __restrict__ dp_table,
                       const int* __restrict__ dp_in,
                       const float* __restrict__ feat,
                       const int* __restrict__ pred_idx,
                       float* __restrict__ inp) {
  const int t = blockIdx.x;
  const int c = threadIdx.x;  // 0..255 -> col 100+c
  if (c >= 204) return;
  const int col = 100 + c;
  float v;
  if (col < 200)      v = inp[(size_t)pred_idx[0] * LDA0 + (col - 100)];
  else if (col < 264) v = dp_table[dp_in[t] * 64 + (col - 200)];
  else if (col < 300) v = feat[t * 36 + (col - 264)];
  else                v = 0.0f;  // pad cols 300..303
  inp[(size_t)t * LDA0 + col] = v;
}

// ---------------- kernel 3: xp[M x 1024] = A[M x K] @ [Wf;Wb]^T + [bf;bb]
__global__ __launch_bounds__(256) void k_gemm(
    const float* __restrict__ A, int lda, int K,
    const float* __restrict__ Wf, const float* __restrict__ Wb,
    const float* __restrict__ bf, const float* __restrict__ bb,
    float* __restrict__ out) {
  constexpr int BK = 16, LDT = 68;
  __shared__ float As[BK][LDT];
  __shared__ float Bs[BK][LDT];
  const int tid = threadIdx.x;
  const int tx = tid & 15, ty = tid >> 4;
  const int bm = blockIdx.x * 64;
  const int n0 = blockIdx.y * 64;
  const float* __restrict__ W  = (n0 < GATES) ? Wf : Wb;
  const float* __restrict__ bs = (n0 < GATES) ? bf : bb;
  const int nw = (n0 < GATES) ? n0 : n0 - GATES;
  const int ar = tid >> 2;
  const int ak = (tid & 3) * 4;
  float acc[4][4] = {};
  const int ktiles = (K + BK - 1) / BK;
  for (int kt = 0; kt < ktiles; ++kt) {
    const int k0 = kt * BK;
    float4 av = *(const float4*)&A[(size_t)(bm + ar) * lda + k0 + ak];
    float4 bv = make_float4(0.f, 0.f, 0.f, 0.f);
    if (k0 + ak < K)
      bv = *(const float4*)&W[(size_t)(nw + ar) * K + k0 + ak];
    __syncthreads();
    As[ak + 0][ar] = av.x; As[ak + 1][ar] = av.y;
    As[ak + 2][ar] = av.z; As[ak + 3][ar] = av.w;
    Bs[ak + 0][ar] = bv.x; Bs[ak + 1][ar] = bv.y;
    Bs[ak + 2][ar] = bv.z; Bs[ak + 3][ar] = bv.w;
    __syncthreads();
#pragma unroll
    for (int kk = 0; kk < BK; ++kk) {
      float4 a4 = *(const float4*)&As[kk][ty * 4];
      float4 b4 = *(const float4*)&Bs[kk][tx * 4];
      float a_[4] = {a4.x, a4.y, a4.z, a4.w};
      float b_[4] = {b4.x, b4.y, b4.z, b4.w};
#pragma unroll
      for (int i = 0; i < 4; ++i)
#pragma unroll
        for (int j = 0; j < 4; ++j)
          acc[i][j] = fmaf(a_[i], b_[j], acc[i][j]);
    }
  }
  const float4 bias4 = *(const float4*)&bs[nw + tx * 4];
#pragma unroll
  for (int i = 0; i < 4; ++i) {
    float4 o;
    o.x = acc[i][0] + bias4.x;
    o.y = acc[i][1] + bias4.y;
    o.z = acc[i][2] + bias4.z;
    o.w = acc[i][3] + bias4.w;
    *(float4*)&out[(size_t)(bm + ty * 4 + i) * XPD + n0 + tx * 4] = o;
  }
}

// ---------------- kernel 4: persistent LSTM recurrence, one block per direction
// 512 threads = 8 waves, __launch_bounds__(512, 2): 2 waves/SIMD min -> VGPR
// cap 256 (arch max). One gate row/thread: weights = 128 VGPRs + xp prefetch
// 16 + temps ~ 180 total -> NO spill (round 1 failed here with cap 88, round 2
// with 2 rows/thread = 256 weight regs > arch ceiling).
__global__ __launch_bounds__(512, 2) void k_lstm(
    const float* __restrict__ xp,     // [T][1024] (f cols 0:512, b cols 512:1024)
    const float* __restrict__ whh_f,  // [512][128]
    const float* __restrict__ whh_b,
    float* __restrict__ hout) {       // [T][256] (f cols 0:128, b cols 128:256)
  const int dir = blockIdx.x;
  const int r = threadIdx.x;  // gate row 0..511
  const float* __restrict__ whh = dir ? whh_b : whh_f;
  const int xofs = dir * GATES;
  const int hofs = dir * HID;

  __shared__ __align__(16) float lh[HID];
  __shared__ float lg[GATES];

  // persistent weights: one gate row per thread, 128 VGPRs
  float4 w4[32];
  {
    const float4* wrow = (const float4*)(whh + (size_t)r * HID);
#pragma unroll
    for (int q = 0; q < 32; ++q) w4[q] = wrow[q];
  }

  float c = 0.0f;
  if (r < HID) lh[r] = 0.0f;
  __syncthreads();

  float xcur[8], xnxt[8];
#pragma unroll
  for (int u = 0; u < 8; ++u) {
    const int tt = dir ? (T_SEQ - 1 - u) : u;
    xcur[u] = xp[(size_t)tt * XPD + xofs + r];
  }

  for (int t0 = 0; t0 < T_SEQ; t0 += 8) {
    // prefetch next group of xp (raw barriers below keep these in flight)
    const int tb = (t0 + 8 < T_SEQ) ? t0 + 8 : 0;
#pragma unroll
    for (int u = 0; u < 8; ++u) {
      const int t = tb + u;
      const int tt = dir ? (T_SEQ - 1 - t) : t;
      xnxt[u] = xp[(size_t)tt * XPD + xofs + r];
    }
#pragma unroll
    for (int u = 0; u < 8; ++u) {
      const int t = t0 + u;
      const int tt = dir ? (T_SEQ - 1 - t) : t;
      // dot(w_row, h_prev): 32 broadcast ds_read_b128 + 128 FMA, 4 chains
      const float4* lh4 = (const float4*)lh;
      float ax = 0.f, ay = 0.f, az = 0.f, aw = 0.f;
#pragma unroll
      for (int q = 0; q < 32; ++q) {
        float4 hv = lh4[q];
        ax = fmaf(w4[q].x, hv.x, ax);
        ay = fmaf(w4[q].y, hv.y, ay);
        az = fmaf(w4[q].z, hv.z, az);
        aw = fmaf(w4[q].w, hv.w, aw);
      }
      float g = xcur[u] + ((ax + ay) + (az + aw));
      // apply own gate nonlinearity before staging (wave-uniform branch)
      float gn = (r < 2 * HID) ? sigm(g) : (r < 3 * HID) ? tanh_f(g) : sigm(g);
      lg[r] = gn;
      asm volatile("s_waitcnt lgkmcnt(0)" ::: "memory");
      __builtin_amdgcn_s_barrier();
      if (r < HID) {
        float gi = lg[r];
        float gf = lg[HID + r];
        float gg = lg[2 * HID + r];
        float go = lg[3 * HID + r];
        c = gf * c + gi * gg;
        float h = go * tanh_f(c);
        lh[r] = h;
        hout[(size_t)tt * 256 + hofs + r] = h;  // fire-and-forget store
      }
      asm volatile("s_waitcnt lgkmcnt(0)" ::: "memory");
      __builtin_amdgcn_s_barrier();
      xcur[u] = xnxt[u];
    }
  }
}

// ---------------- kernel 5: tag_space = h2 @ W_out^T + b_out
__global__ void k_out(const float* __restrict__ h2,
                      const float* __restrict__ Wout,
                      const float* __restrict__ bout,
                      float* __restrict__ out) {
  __shared__ __align__(16) float hrow[256];
  const int t = blockIdx.x;
  const int tid = threadIdx.x;  // 64
  *(float4*)&hrow[tid * 4] = *(const float4*)&h2[(size_t)t * 256 + tid * 4];
  __syncthreads();
  if (tid < TAGS) {
    float acc = bout[tid];
    const float* w = &Wout[(size_t)tid * 256];
#pragma unroll 8
    for (int k = 0; k < 256; k += 4) {
      float4 wv = *(const float4*)&w[k];
      acc += hrow[k] * wv.x + hrow[k + 1] * wv.y + hrow[k + 2] * wv.z +
             hrow[k + 3] * wv.w;
    }
    out[(size_t)t * TAGS + tid] = acc;
  }
}

extern "C" void kernel_launch(void* const* d_in, const int* in_sizes, int n_in,
                              void* d_out, int out_size, void* d_ws, size_t ws_size,
                              hipStream_t stream) {
  const int*   morp_ids = (const int*)d_in[0];
  const int*   seg      = (const int*)d_in[1];
  const int*   pred_idx = (const int*)d_in[2];
  const int*   dp_in    = (const int*)d_in[3];
  const float* feat     = (const float*)d_in[4];
  const float* W_wv     = (const float*)d_in[5];
  const float* dp_table = (const float*)d_in[6];
  const float* W_out    = (const float*)d_in[7];
  const float* b_out    = (const float*)d_in[8];
  const float* w_ih_l0f = (const float*)d_in[9];
  const float* w_hh_l0f = (const float*)d_in[10];
  const float* b_l0f    = (const float*)d_in[11];
  const float* w_ih_l0b = (const float*)d_in[12];
  const float* w_hh_l0b = (const float*)d_in[13];
  const float* b_l0b    = (const float*)d_in[14];
  const float* w_ih_l1f = (const float*)d_in[15];
  const float* w_hh_l1f = (const float*)d_in[16];
  const float* b_l1f    = (const float*)d_in[17];
  const float* w_ih_l1b = (const float*)d_in[18];
  const float* w_hh_l1b = (const float*)d_in[19];
  const float* b_l1b    = (const float*)d_in[20];
  float* out = (float*)d_out;

  float* ws  = (float*)d_ws;
  float* inp = ws;                      // 2048*304
  float* xp  = inp + 2048 * LDA0;       // 2048*1024 (reused for both layers)
  float* h1  = xp + 2048 * XPD;         // 2048*256
  float* h2  = h1 + 2048 * 256;         // 2048*256

  k_toksum<<<2048, 128, 0, stream>>>(W_wv, morp_ids, seg, inp);
  k_fill<<<2048, 256, 0, stream>>>(dp_table, dp_in, feat, pred_idx, inp);

  dim3 gg(32, 16);
  k_gemm<<<gg, 256, 0, stream>>>(inp, LDA0, 300, w_ih_l0f, w_ih_l0b, b_l0f, b_l0b, xp);
  k_lstm<<<2, 512, 0, stream>>>(xp, w_hh_l0f, w_hh_l0b, h1);
  k_gemm<<<gg, 256, 0, stream>>>(h1, 256, 256, w_ih_l1f, w_ih_l1b, b_l1f, b_l1b, xp);
  k_lstm<<<2, 512, 0, stream>>>(xp, w_hh_l1f, w_hh_l1b, h2);
  k_out<<<2048, 64, 0, stream>>>(h2, W_out, b_out, out);
}